// Round 1
// baseline (1200.781 us; speedup 1.0000x reference)
//
#include <hip/hip_runtime.h>
#include <hip/hip_bf16.h>

// Problem constants (fixed instance)
#define B_    64
#define N_    1024
#define NT_   100
#define DIM_  256
#define KD_   16
#define NH_   8
#define D_    64
#define DH_   512      // D*NH
#define NHKD_ 128      // KD*NH
#define HKV_  640      // DH + NHKD
#define PROJIN_ 1512
#define KCAT_ 1312     // DH + NH*NT (zero-pad cols skipped)
#define EPS_  1e-5f
#define M_    (B_*N_)  // 65536

__device__ __forceinline__ float bf_lo(unsigned int p){
    union { unsigned int i; float f; } c; c.i = p << 16; return c.f;
}
__device__ __forceinline__ float bf_hi(unsigned int p){
    union { unsigned int i; float f; } c; c.i = p & 0xffff0000u; return c.f;
}
__device__ __forceinline__ int iabs(int x){ return x < 0 ? -x : x; }

// ---------------- K1: kv = BN(x @ kv_w^T) -> bf16 (M_ x HKV_) ----------------
__global__ __launch_bounds__(256) void k1_kv(
    const float* __restrict__ x, const float* __restrict__ kv_w,
    const float* __restrict__ g, const float* __restrict__ bb,
    const float* __restrict__ mn, const float* __restrict__ vr,
    __hip_bfloat16* __restrict__ kv_out)
{
    __shared__ float As[16][64];
    __shared__ float Bs[16][64];
    const int tid = threadIdx.x;
    const int m0 = blockIdx.y * 64;
    const int j0 = blockIdx.x * 64;
    const int r  = tid >> 2, kq = tid & 3;
    const int tx = tid & 15, ty = tid >> 4;
    float acc[4][4] = {};

    for (int k0 = 0; k0 < DIM_; k0 += 16) {
        float4 av = *(const float4*)(x    + (size_t)(m0 + r) * DIM_ + k0 + kq * 4);
        float4 bv = *(const float4*)(kv_w + (size_t)(j0 + r) * DIM_ + k0 + kq * 4);
        __syncthreads();
        As[kq*4+0][r] = av.x; As[kq*4+1][r] = av.y; As[kq*4+2][r] = av.z; As[kq*4+3][r] = av.w;
        Bs[kq*4+0][r] = bv.x; Bs[kq*4+1][r] = bv.y; Bs[kq*4+2][r] = bv.z; Bs[kq*4+3][r] = bv.w;
        __syncthreads();
        #pragma unroll
        for (int kk = 0; kk < 16; kk++) {
            float4 a = *(const float4*)&As[kk][ty*4];
            float4 b = *(const float4*)&Bs[kk][tx*4];
            float ar[4] = {a.x,a.y,a.z,a.w}, br[4] = {b.x,b.y,b.z,b.w};
            #pragma unroll
            for (int i = 0; i < 4; i++)
                #pragma unroll
                for (int j = 0; j < 4; j++)
                    acc[i][j] += ar[i] * br[j];
        }
    }
    #pragma unroll
    for (int jj = 0; jj < 4; jj++) {
        const int j = j0 + tx*4 + jj;
        const float s = g[j] * rsqrtf(vr[j] + EPS_);
        const float o = bb[j] - mn[j] * s;
        #pragma unroll
        for (int ii = 0; ii < 4; ii++) {
            const int m = m0 + ty*4 + ii;
            kv_out[(size_t)m * HKV_ + j] = __float2bfloat16(acc[ii][jj] * s + o);
        }
    }
}

// ---------------- K2: q = BN(text @ q_w^T) -> f32 (NT_ x 128) ----------------
__global__ __launch_bounds__(128) void k2_q(
    const float* __restrict__ text, const float* __restrict__ q_w,
    const float* __restrict__ g, const float* __restrict__ bb,
    const float* __restrict__ mn, const float* __restrict__ vr,
    float* __restrict__ q_out)
{
    __shared__ float ts[DIM_];
    const int t = blockIdx.x, j = threadIdx.x;
    for (int i = threadIdx.x; i < DIM_; i += 128) ts[i] = text[t * DIM_ + i];
    __syncthreads();
    float acc = 0.f;
    for (int k = 0; k < DIM_; k++) acc += ts[k] * q_w[j * DIM_ + k];
    const float s = g[j] * rsqrtf(vr[j] + EPS_);
    q_out[t * 128 + j] = acc * s + (bb[j] - mn[j] * s);
}

// ---------------- K3: attn = softmax(q.k*0.25 + bias) -> bf16 (B,NH,NT,N) ----
__global__ __launch_bounds__(256) void k3_attn(
    const __hip_bfloat16* __restrict__ kv, const float* __restrict__ qb,
    const float* __restrict__ biases, const int* __restrict__ Wp,
    __hip_bfloat16* __restrict__ attn)
{
    __shared__ unsigned int ks[N_ * 8];   // 1024 rows x 16 bf16 (8 u32)
    __shared__ float qs[NT_ * KD_];
    __shared__ float bs[3200];
    const int bh = blockIdx.x, b = bh >> 3, h = bh & 7;
    const int tid = threadIdx.x;
    const int w = *Wp;

    for (int n = tid; n < N_; n += 256) {
        const uint4* p = (const uint4*)(kv + (size_t)(b * N_ + n) * HKV_ + h * 80);
        uint4* dst = (uint4*)&ks[n * 8];
        dst[0] = p[0]; dst[1] = p[1];
    }
    for (int i = tid; i < NT_ * KD_; i += 256) {
        const int t = i >> 4, d = i & 15;
        qs[i] = qb[t * 128 + h * 16 + d];
    }
    for (int i = tid; i < 3200; i += 256) bs[i] = biases[h * 10000 + i];
    __syncthreads();

    const int wid = tid >> 6, lane = tid & 63;
    // per-lane n positions (fixed across t)
    int pxm[16], py[16];
    #pragma unroll
    for (int rr = 0; rr < 16; rr++) {
        const int n = rr * 64 + lane;
        const int px = n / w;
        pxm[rr] = px * 100;
        py[rr]  = n - px * w;
    }
    for (int t = wid; t < NT_; t += 4) {
        float q[16];
        #pragma unroll
        for (int d = 0; d < 16; d++) q[d] = qs[t * 16 + d];
        float l[16]; float mx = -1e30f;
        #pragma unroll
        for (int rr = 0; rr < 16; rr++) {
            const int n = rr * 64 + lane;
            float acc = 0.f;
            #pragma unroll
            for (int p = 0; p < 8; p++) {
                const unsigned int u = ks[n * 8 + p];
                acc += bf_lo(u) * q[2*p] + bf_hi(u) * q[2*p+1];
            }
            l[rr] = acc * 0.25f + bs[pxm[rr] + iabs(t - py[rr])];
            mx = fmaxf(mx, l[rr]);
        }
        #pragma unroll
        for (int o = 32; o > 0; o >>= 1) mx = fmaxf(mx, __shfl_xor(mx, o));
        float sum = 0.f;
        #pragma unroll
        for (int rr = 0; rr < 16; rr++) { l[rr] = __expf(l[rr] - mx); sum += l[rr]; }
        #pragma unroll
        for (int o = 32; o > 0; o >>= 1) sum += __shfl_xor(sum, o);
        const float inv = 1.0f / sum;
        const size_t base = ((size_t)((b * 8 + h) * 100 + t)) * N_;
        #pragma unroll
        for (int rr = 0; rr < 16; rr++)
            attn[base + rr * 64 + lane] = __float2bfloat16(l[rr] * inv);
    }
}

// ------- K4: out = BN(hardswish(v_cat) @ proj_w^T) -> f32 (M_ x 256) ---------
__global__ __launch_bounds__(256) void k4_proj(
    const __hip_bfloat16* __restrict__ kv, const __hip_bfloat16* __restrict__ attn,
    const float* __restrict__ proj_w,
    const float* __restrict__ g, const float* __restrict__ bb,
    const float* __restrict__ mn, const float* __restrict__ vr,
    float* __restrict__ out)
{
    __shared__ float As[16][64];
    __shared__ float Bs[16][64];
    const int tid = threadIdx.x;
    const int m0 = blockIdx.y * 64;
    const int o0 = blockIdx.x * 64;
    const int r  = tid >> 2, kq = tid & 3;
    const int tx = tid & 15, ty = tid >> 4;
    const int m = m0 + r;
    const int bidx = m >> 10, n = m & 1023;
    float acc[4][4] = {};

    for (int c0 = 0; c0 < KCAT_; c0 += 16) {
        float av[4];
        #pragma unroll
        for (int u = 0; u < 4; u++) {
            const int c = c0 + kq * 4 + u;
            float val;
            if (c < DH_) {
                const int h = c >> 6, d = c & 63;
                val = __bfloat162float(kv[(size_t)m * HKV_ + h * 80 + 16 + d]);
            } else {
                const int cc = c - DH_;
                const int h = cc / 100, t = cc - h * 100;
                val = __bfloat162float(attn[((size_t)((bidx * 8 + h) * 100 + t)) * N_ + n]);
            }
            float t3 = fminf(fmaxf(val + 3.0f, 0.f), 6.f);
            av[u] = val * t3 * (1.f / 6.f);
        }
        float4 bv = *(const float4*)(proj_w + (size_t)(o0 + r) * PROJIN_ + c0 + kq * 4);
        __syncthreads();
        As[kq*4+0][r] = av[0]; As[kq*4+1][r] = av[1]; As[kq*4+2][r] = av[2]; As[kq*4+3][r] = av[3];
        Bs[kq*4+0][r] = bv.x;  Bs[kq*4+1][r] = bv.y;  Bs[kq*4+2][r] = bv.z;  Bs[kq*4+3][r] = bv.w;
        __syncthreads();
        #pragma unroll
        for (int kk = 0; kk < 16; kk++) {
            float4 a = *(const float4*)&As[kk][ty*4];
            float4 b = *(const float4*)&Bs[kk][tx*4];
            float ar[4] = {a.x,a.y,a.z,a.w}, br[4] = {b.x,b.y,b.z,b.w};
            #pragma unroll
            for (int i = 0; i < 4; i++)
                #pragma unroll
                for (int j = 0; j < 4; j++)
                    acc[i][j] += ar[i] * br[j];
        }
    }
    #pragma unroll
    for (int jj = 0; jj < 4; jj++) {
        const int o = o0 + tx*4 + jj;
        const float s = g[o] * rsqrtf(vr[o] + EPS_);
        const float ofs = bb[o] - mn[o] * s;
        #pragma unroll
        for (int ii = 0; ii < 4; ii++) {
            const int mm = m0 + ty*4 + ii;
            out[(size_t)mm * DIM_ + o] = acc[ii][jj] * s + ofs;
        }
    }
}

extern "C" void kernel_launch(void* const* d_in, const int* in_sizes, int n_in,
                              void* d_out, int out_size, void* d_ws, size_t ws_size,
                              hipStream_t stream) {
    const float* x      = (const float*)d_in[0];
    const float* text   = (const float*)d_in[1];
    const float* kv_w   = (const float*)d_in[2];
    const float* kv_g   = (const float*)d_in[3];
    const float* kv_b   = (const float*)d_in[4];
    const float* kv_m   = (const float*)d_in[5];
    const float* kv_v   = (const float*)d_in[6];
    const float* q_w    = (const float*)d_in[7];
    const float* q_g    = (const float*)d_in[8];
    const float* q_b    = (const float*)d_in[9];
    const float* q_m    = (const float*)d_in[10];
    const float* q_v    = (const float*)d_in[11];
    const float* proj_w = (const float*)d_in[12];
    const float* proj_g = (const float*)d_in[13];
    const float* proj_b = (const float*)d_in[14];
    const float* proj_m = (const float*)d_in[15];
    const float* proj_v = (const float*)d_in[16];
    const float* biases = (const float*)d_in[17];
    const int*   Wp     = (const int*)d_in[19];
    float* out = (float*)d_out;

    // workspace carve (bytes): kv bf16 83,886,080 | attn bf16 104,857,600 | q f32 51,200
    char* w = (char*)d_ws;
    __hip_bfloat16* kv_buf   = (__hip_bfloat16*)(w);
    __hip_bfloat16* attn_buf = (__hip_bfloat16*)(w + (size_t)M_ * HKV_ * 2);
    float*          q_buf    = (float*)(w + (size_t)M_ * HKV_ * 2 + (size_t)B_ * NH_ * NT_ * N_ * 2);

    k1_kv<<<dim3(HKV_/64, M_/64), 256, 0, stream>>>(x, kv_w, kv_g, kv_b, kv_m, kv_v, kv_buf);
    k2_q<<<dim3(NT_), 128, 0, stream>>>(text, q_w, q_g, q_b, q_m, q_v, q_buf);
    k3_attn<<<dim3(B_*NH_), 256, 0, stream>>>(kv_buf, q_buf, biases, Wp, attn_buf);
    k4_proj<<<dim3(DIM_/64, M_/64), 256, 0, stream>>>(kv_buf, attn_buf, proj_w,
                                                      proj_g, proj_b, proj_m, proj_v, out);
}

// Round 3
// 453.596 us; speedup vs baseline: 2.6472x; 2.6472x over previous
//
#include <hip/hip_runtime.h>
#include <hip/hip_bf16.h>

#define B_    64
#define N_    1024
#define NT_   100
#define DIM_  256
#define KD_   16
#define NH_   8
#define D_    64
#define DH_   512
#define HKV_  640
#define PROJIN_ 1512
#define KCAT_ 1312
#define EPS_  1e-5f
#define M_    (B_*N_)

typedef __attribute__((ext_vector_type(8))) short bf16x8;
typedef __attribute__((ext_vector_type(4))) float f32x4;

__device__ __forceinline__ float bf_lo(unsigned int p){ union{unsigned int i;float f;}c; c.i=p<<16; return c.f; }
__device__ __forceinline__ float bf_hi(unsigned int p){ union{unsigned int i;float f;}c; c.i=p&0xffff0000u; return c.f; }
__device__ __forceinline__ int iabs(int x){ return x<0?-x:x; }
__device__ __forceinline__ unsigned short bfr(float f){ __hip_bfloat16 h=__float2bfloat16(f); return *(unsigned short*)&h; }

#define GLDS16(src, dst) __builtin_amdgcn_global_load_lds( \
    (const __attribute__((address_space(1))) void*)(src),  \
    (__attribute__((address_space(3))) void*)(dst), 16, 0, 0)

// ---------------- P0: f32 -> bf16 conversions -------------------------------
__global__ __launch_bounds__(256) void p0_cvt(
    const float* __restrict__ x, const float* __restrict__ kvw, const float* __restrict__ pw,
    unsigned short* __restrict__ xb, unsigned short* __restrict__ kvwb, unsigned short* __restrict__ pwb)
{
    const size_t stride = (size_t)gridDim.x * 256;
    const size_t i0 = (size_t)blockIdx.x * 256 + threadIdx.x;
    for (size_t q = i0; q < (size_t)M_*DIM_/4; q += stride) {
        float4 v = ((const float4*)x)[q];
        ushort4 o; o.x=bfr(v.x); o.y=bfr(v.y); o.z=bfr(v.z); o.w=bfr(v.w);
        ((ushort4*)xb)[q] = o;
    }
    for (size_t q = i0; q < (size_t)HKV_*DIM_/4; q += stride) {
        float4 v = ((const float4*)kvw)[q];
        ushort4 o; o.x=bfr(v.x); o.y=bfr(v.y); o.z=bfr(v.z); o.w=bfr(v.w);
        ((ushort4*)kvwb)[q] = o;
    }
    for (size_t q = i0; q < (size_t)DIM_*KCAT_/4; q += stride) {
        const int row = (int)(q / (KCAT_/4)), cq = (int)(q % (KCAT_/4));
        float4 v = ((const float4*)(pw + (size_t)row*PROJIN_))[cq];
        ushort4 o; o.x=bfr(v.x); o.y=bfr(v.y); o.z=bfr(v.z); o.w=bfr(v.w);
        ((ushort4*)pwb)[q] = o;
    }
}

// ---------------- K1: kv = BN(x @ kv_w^T), bf16 MFMA ------------------------
__global__ __launch_bounds__(256,2) void k1g(
    const unsigned short* __restrict__ xb, const unsigned short* __restrict__ wb,
    const float* __restrict__ g, const float* __restrict__ bb,
    const float* __restrict__ mn, const float* __restrict__ vr,
    __hip_bfloat16* __restrict__ outC)
{
    __shared__ unsigned short As[128*32];
    __shared__ unsigned short Bs[128*32];
    const int tid = threadIdx.x;
    const int wave = tid >> 6, lane = tid & 63;
    const int m0 = blockIdx.y * 128, n0 = blockIdx.x * 128;
    const int wm = (wave >> 1) * 64, wn = (wave & 1) * 64;
    const int srow = lane >> 2, scol = (lane & 3) * 8;
    f32x4 acc[4][4];
    #pragma unroll
    for (int i=0;i<4;i++)
        #pragma unroll
        for (int j=0;j<4;j++) acc[i][j] = (f32x4){0.f,0.f,0.f,0.f};

    for (int k0 = 0; k0 < DIM_; k0 += 32) {
        #pragma unroll
        for (int i = 0; i < 2; i++) {
            const int rr = (wave*2 + i)*16 + srow;
            GLDS16(xb + (size_t)(m0+rr)*DIM_ + k0 + scol, As + (wave*2+i)*512);
            GLDS16(wb + (size_t)(n0+rr)*DIM_ + k0 + scol, Bs + (wave*2+i)*512);
        }
        __syncthreads();
        bf16x8 af[4], bfv[4];
        #pragma unroll
        for (int f = 0; f < 4; f++) {
            af[f]  = *(const bf16x8*)&As[(wm + f*16 + (lane&15))*32 + (lane>>4)*8];
            bfv[f] = *(const bf16x8*)&Bs[(wn + f*16 + (lane&15))*32 + (lane>>4)*8];
        }
        #pragma unroll
        for (int fi = 0; fi < 4; fi++)
            #pragma unroll
            for (int fj = 0; fj < 4; fj++)
                acc[fi][fj] = __builtin_amdgcn_mfma_f32_16x16x32_bf16(af[fi], bfv[fj], acc[fi][fj], 0,0,0);
        __syncthreads();
    }
    #pragma unroll
    for (int fj = 0; fj < 4; fj++) {
        const int col = n0 + wn + fj*16 + (lane & 15);
        const float s = g[col] * rsqrtf(vr[col] + EPS_);
        const float o = bb[col] - mn[col] * s;
        #pragma unroll
        for (int fi = 0; fi < 4; fi++)
            #pragma unroll
            for (int r = 0; r < 4; r++) {
                const int m = m0 + wm + fi*16 + (lane>>4)*4 + r;
                outC[(size_t)m * HKV_ + col] = __float2bfloat16(acc[fi][fj][r] * s + o);
            }
    }
}

// ---------------- K2: q = BN(text @ q_w^T) -> f32 (NT_ x 128) ----------------
__global__ __launch_bounds__(128) void k2_q(
    const float* __restrict__ text, const float* __restrict__ q_w,
    const float* __restrict__ g, const float* __restrict__ bb,
    const float* __restrict__ mn, const float* __restrict__ vr,
    float* __restrict__ q_out)
{
    __shared__ float ts[DIM_];
    const int t = blockIdx.x, j = threadIdx.x;
    for (int i = threadIdx.x; i < DIM_; i += 128) ts[i] = text[t * DIM_ + i];
    __syncthreads();
    float acc = 0.f;
    for (int k = 0; k < DIM_; k++) acc += ts[k] * q_w[j * DIM_ + k];
    const float s = g[j] * rsqrtf(vr[j] + EPS_);
    q_out[t * 128 + j] = acc * s + (bb[j] - mn[j] * s);
}

// -------- K3: attn = hswish(softmax(q.k*0.25 + bias)) -> bf16 (B,NH,NT,N) ----
__global__ __launch_bounds__(256) void k3_attn(
    const __hip_bfloat16* __restrict__ kv, const float* __restrict__ qb,
    const float* __restrict__ biases, const int* __restrict__ Wp,
    __hip_bfloat16* __restrict__ attn)
{
    __shared__ unsigned int ks[N_ * 8];
    __shared__ float qs[NT_ * KD_];
    __shared__ float bs[3200];
    const int bh = blockIdx.x, b = bh >> 3, h = bh & 7;
    const int tid = threadIdx.x;
    const int w = *Wp;

    for (int n = tid; n < N_; n += 256) {
        const uint4* p = (const uint4*)(kv + (size_t)(b * N_ + n) * HKV_ + h * 80);
        uint4* dst = (uint4*)&ks[n * 8];
        dst[0] = p[0]; dst[1] = p[1];
    }
    for (int i = tid; i < NT_ * KD_; i += 256) {
        const int t = i >> 4, d = i & 15;
        qs[i] = qb[t * 128 + h * 16 + d];
    }
    for (int i = tid; i < 3200; i += 256) bs[i] = biases[h * 10000 + i];
    __syncthreads();

    const int wid = tid >> 6, lane = tid & 63;
    int pxm[16], py[16];
    #pragma unroll
    for (int rr = 0; rr < 16; rr++) {
        const int n = rr * 64 + lane;
        const int px = n / w;
        pxm[rr] = px * 100;
        py[rr]  = n - px * w;
    }
    for (int t = wid; t < NT_; t += 4) {
        float q[16];
        #pragma unroll
        for (int d = 0; d < 16; d++) q[d] = qs[t * 16 + d];
        float l[16]; float mx = -1e30f;
        #pragma unroll
        for (int rr = 0; rr < 16; rr++) {
            const int n = rr * 64 + lane;
            float acc = 0.f;
            #pragma unroll
            for (int p = 0; p < 8; p++) {
                const unsigned int u = ks[n * 8 + p];
                acc += bf_lo(u) * q[2*p] + bf_hi(u) * q[2*p+1];
            }
            l[rr] = acc * 0.25f + bs[pxm[rr] + iabs(t - py[rr])];
            mx = fmaxf(mx, l[rr]);
        }
        #pragma unroll
        for (int o = 32; o > 0; o >>= 1) mx = fmaxf(mx, __shfl_xor(mx, o));
        float sum = 0.f;
        #pragma unroll
        for (int rr = 0; rr < 16; rr++) { l[rr] = __expf(l[rr] - mx); sum += l[rr]; }
        #pragma unroll
        for (int o = 32; o > 0; o >>= 1) sum += __shfl_xor(sum, o);
        const float inv = 1.0f / sum;
        const size_t base = ((size_t)((b * 8 + h) * 100 + t)) * N_;
        #pragma unroll
        for (int rr = 0; rr < 16; rr++) {
            const float pv = l[rr] * inv;                       // in [0,1]
            attn[base + rr * 64 + lane] = __float2bfloat16(pv * (pv + 3.f) * (1.f/6.f));
        }
    }
}

// -------- K4: out = BN(hardswish(v_cat) @ proj_w^T), bf16 MFMA ---------------
__global__ __launch_bounds__(512,2) void k4g(
    const __hip_bfloat16* __restrict__ kv, const __hip_bfloat16* __restrict__ attn,
    const unsigned short* __restrict__ pwb,
    const float* __restrict__ g, const float* __restrict__ bb,
    const float* __restrict__ mn, const float* __restrict__ vr,
    float* __restrict__ out)
{
    __shared__ unsigned short As[128*32];
    __shared__ unsigned short Bs[256*32];
    const int tid = threadIdx.x;
    const int wave = tid >> 6, lane = tid & 63;
    const int m0 = blockIdx.x * 128;
    const int b  = blockIdx.x >> 3;
    const int nb = m0 & (N_-1);
    const int wm = (wave >> 2) * 64, wn = (wave & 3) * 64;
    const int srow = lane >> 2, scol = (lane & 3) * 8;
    const int arow = tid >> 2, akoff = (tid & 3) * 8;  // v-part mapping
    const int ac = tid >> 4, amb = (tid & 15) * 8;     // attn-part mapping
    f32x4 acc[4][4];
    #pragma unroll
    for (int i=0;i<4;i++)
        #pragma unroll
        for (int j=0;j<4;j++) acc[i][j] = (f32x4){0.f,0.f,0.f,0.f};

    for (int ks = 0; ks < KCAT_/32; ks++) {
        const int k0 = ks * 32;
        // B tile: global_load_lds, 256 rows x 32 cols
        #pragma unroll
        for (int i = 0; i < 2; i++) {
            const int rr = (wave*2 + i)*16 + srow;
            GLDS16(pwb + (size_t)rr*KCAT_ + k0 + scol, Bs + (wave*2+i)*512);
        }
        // A tile: register-staged
        if (k0 < DH_) {
            const int c = k0 + akoff;
            const int h = c >> 6, d = c & 63;
            uint4 raw = *(const uint4*)(kv + (size_t)(m0+arow)*HKV_ + h*80 + 16 + d);
            const unsigned int* u = (const unsigned int*)&raw;
            ushort4 o0, o1;
            unsigned short vals[8];
            #pragma unroll
            for (int j = 0; j < 4; j++) {
                float a = bf_lo(u[j]), bv = bf_hi(u[j]);
                a  = a  * fminf(fmaxf(a  + 3.f, 0.f), 6.f) * (1.f/6.f);
                bv = bv * fminf(fmaxf(bv + 3.f, 0.f), 6.f) * (1.f/6.f);
                vals[2*j] = bfr(a); vals[2*j+1] = bfr(bv);
            }
            o0.x=vals[0]; o0.y=vals[1]; o0.z=vals[2]; o0.w=vals[3];
            o1.x=vals[4]; o1.y=vals[5]; o1.z=vals[6]; o1.w=vals[7];
            *(ushort4*)&As[arow*32 + akoff]     = o0;
            *(ushort4*)&As[arow*32 + akoff + 4] = o1;
        } else {
            const int cc = k0 - DH_ + ac;
            const int h = cc / 100, t = cc - h*100;
            uint4 raw = *(const uint4*)(attn + ((size_t)((b*NH_ + h)*NT_ + t))*N_ + nb + amb);
            const unsigned short* u16 = (const unsigned short*)&raw;
            #pragma unroll
            for (int j = 0; j < 8; j++)
                As[(amb + j)*32 + ac] = u16[j];
        }
        __syncthreads();
        bf16x8 af[4], bfv[4];
        #pragma unroll
        for (int f = 0; f < 4; f++) {
            af[f]  = *(const bf16x8*)&As[(wm + f*16 + (lane&15))*32 + (lane>>4)*8];
            bfv[f] = *(const bf16x8*)&Bs[(wn + f*16 + (lane&15))*32 + (lane>>4)*8];
        }
        #pragma unroll
        for (int fi = 0; fi < 4; fi++)
            #pragma unroll
            for (int fj = 0; fj < 4; fj++)
                acc[fi][fj] = __builtin_amdgcn_mfma_f32_16x16x32_bf16(af[fi], bfv[fj], acc[fi][fj], 0,0,0);
        __syncthreads();
    }
    #pragma unroll
    for (int fj = 0; fj < 4; fj++) {
        const int col = wn + fj*16 + (lane & 15);
        const float s = g[col] * rsqrtf(vr[col] + EPS_);
        const float o = bb[col] - mn[col] * s;
        #pragma unroll
        for (int fi = 0; fi < 4; fi++)
            #pragma unroll
            for (int r = 0; r < 4; r++) {
                const int m = m0 + wm + fi*16 + (lane>>4)*4 + r;
                out[(size_t)m * DIM_ + col] = acc[fi][fj][r] * s + o;
            }
    }
}

extern "C" void kernel_launch(void* const* d_in, const int* in_sizes, int n_in,
                              void* d_out, int out_size, void* d_ws, size_t ws_size,
                              hipStream_t stream) {
    const float* x      = (const float*)d_in[0];
    const float* text   = (const float*)d_in[1];
    const float* kv_w   = (const float*)d_in[2];
    const float* kv_g   = (const float*)d_in[3];
    const float* kv_b   = (const float*)d_in[4];
    const float* kv_m   = (const float*)d_in[5];
    const float* kv_v   = (const float*)d_in[6];
    const float* q_w    = (const float*)d_in[7];
    const float* q_g    = (const float*)d_in[8];
    const float* q_b    = (const float*)d_in[9];
    const float* q_m    = (const float*)d_in[10];
    const float* q_v    = (const float*)d_in[11];
    const float* proj_w = (const float*)d_in[12];
    const float* proj_g = (const float*)d_in[13];
    const float* proj_b = (const float*)d_in[14];
    const float* proj_m = (const float*)d_in[15];
    const float* proj_v = (const float*)d_in[16];
    const float* biases = (const float*)d_in[17];
    const int*   Wp     = (const int*)d_in[19];
    float* out = (float*)d_out;

    char* w = (char*)d_ws;
    size_t off = 0;
    auto alloc = [&](size_t bytes) { void* p = w + off; off += (bytes + 255) & ~255ull; return p; };
    unsigned short* xb    = (unsigned short*)alloc((size_t)M_*DIM_*2);     // 33.6 MB
    unsigned short* kvwb  = (unsigned short*)alloc((size_t)HKV_*DIM_*2);   // 0.33 MB
    unsigned short* pwb   = (unsigned short*)alloc((size_t)DIM_*KCAT_*2);  // 0.67 MB
    __hip_bfloat16* kvbuf = (__hip_bfloat16*)alloc((size_t)M_*HKV_*2);     // 83.9 MB
    __hip_bfloat16* attnb = (__hip_bfloat16*)alloc((size_t)B_*NH_*NT_*N_*2); // 104.9 MB
    float*          qbuf  = (float*)alloc((size_t)NT_*128*4);

    p0_cvt<<<2048, 256, 0, stream>>>(x, kv_w, proj_w, xb, kvwb, pwb);
    k1g<<<dim3(HKV_/128, M_/128), 256, 0, stream>>>(xb, kvwb, kv_g, kv_b, kv_m, kv_v, kvbuf);
    k2_q<<<NT_, 128, 0, stream>>>(text, q_w, q_g, q_b, q_m, q_v, qbuf);
    k3_attn<<<B_*NH_, 256, 0, stream>>>(kvbuf, qbuf, biases, Wp, attnb);
    k4g<<<M_/128, 512, 0, stream>>>(kvbuf, attnb, pwb, proj_g, proj_b, proj_m, proj_v, out);
}

// Round 4
// 374.890 us; speedup vs baseline: 3.2030x; 1.2099x over previous
//
#include <hip/hip_runtime.h>
#include <hip/hip_bf16.h>

#define B_    64
#define N_    1024
#define NT_   100
#define DIM_  256
#define KD_   16
#define NH_   8
#define D_    64
#define DH_   512
#define HKV_  640
#define PROJIN_ 1512
#define KCAT_ 1312
#define EPS_  1e-5f
#define M_    (B_*N_)

typedef __attribute__((ext_vector_type(8))) short bf16x8;
typedef __attribute__((ext_vector_type(4))) float f32x4;

__device__ __forceinline__ float bf_lo(unsigned int p){ union{unsigned int i;float f;}c; c.i=p<<16; return c.f; }
__device__ __forceinline__ float bf_hi(unsigned int p){ union{unsigned int i;float f;}c; c.i=p&0xffff0000u; return c.f; }
__device__ __forceinline__ int iabs(int x){ return x<0?-x:x; }
__device__ __forceinline__ unsigned short bfr(float f){ __hip_bfloat16 h=__float2bfloat16(f); return *(unsigned short*)&h; }
__device__ __forceinline__ float bfl(unsigned short u){ union{unsigned int i;float f;}c; c.i=(unsigned int)u<<16; return c.f; }

#define GLDS16(src, dst) __builtin_amdgcn_global_load_lds( \
    (const __attribute__((address_space(1))) void*)(src),  \
    (__attribute__((address_space(3))) void*)(dst), 16, 0, 0)

// ---------------- P0: f32 -> bf16 conversions -------------------------------
__global__ __launch_bounds__(256) void p0_cvt(
    const float* __restrict__ x, const float* __restrict__ kvw, const float* __restrict__ pw,
    unsigned short* __restrict__ xb, unsigned short* __restrict__ kvwb, unsigned short* __restrict__ pwb)
{
    const size_t stride = (size_t)gridDim.x * 256;
    const size_t i0 = (size_t)blockIdx.x * 256 + threadIdx.x;
    for (size_t q = i0; q < (size_t)M_*DIM_/4; q += stride) {
        float4 v = ((const float4*)x)[q];
        ushort4 o; o.x=bfr(v.x); o.y=bfr(v.y); o.z=bfr(v.z); o.w=bfr(v.w);
        ((ushort4*)xb)[q] = o;
    }
    for (size_t q = i0; q < (size_t)HKV_*DIM_/4; q += stride) {
        float4 v = ((const float4*)kvw)[q];
        ushort4 o; o.x=bfr(v.x); o.y=bfr(v.y); o.z=bfr(v.z); o.w=bfr(v.w);
        ((ushort4*)kvwb)[q] = o;
    }
    for (size_t q = i0; q < (size_t)DIM_*KCAT_/4; q += stride) {
        const int row = (int)(q / (KCAT_/4)), cq = (int)(q % (KCAT_/4));
        float4 v = ((const float4*)(pw + (size_t)row*PROJIN_))[cq];
        ushort4 o; o.x=bfr(v.x); o.y=bfr(v.y); o.z=bfr(v.z); o.w=bfr(v.w);
        ((ushort4*)pwb)[q] = o;
    }
}

// -------- K1: kv = BN(x @ kv_w^T), bf16 MFMA; hardswish applied to v cols ----
__global__ __launch_bounds__(256,2) void k1g(
    const unsigned short* __restrict__ xb, const unsigned short* __restrict__ wb,
    const float* __restrict__ g, const float* __restrict__ bb,
    const float* __restrict__ mn, const float* __restrict__ vr,
    unsigned short* __restrict__ outC)
{
    __shared__ unsigned short As[128*32];
    __shared__ unsigned short Bs[128*32];
    const int tid = threadIdx.x;
    const int wave = tid >> 6, lane = tid & 63;
    const int m0 = blockIdx.y * 128, n0 = blockIdx.x * 128;
    const int wm = (wave >> 1) * 64, wn = (wave & 1) * 64;
    const int srow = lane >> 2, scol = (lane & 3) * 8;
    f32x4 acc[4][4];
    #pragma unroll
    for (int i=0;i<4;i++)
        #pragma unroll
        for (int j=0;j<4;j++) acc[i][j] = (f32x4){0.f,0.f,0.f,0.f};

    for (int k0 = 0; k0 < DIM_; k0 += 32) {
        #pragma unroll
        for (int i = 0; i < 2; i++) {
            const int rr = (wave*2 + i)*16 + srow;
            GLDS16(xb + (size_t)(m0+rr)*DIM_ + k0 + scol, As + (wave*2+i)*512);
            GLDS16(wb + (size_t)(n0+rr)*DIM_ + k0 + scol, Bs + (wave*2+i)*512);
        }
        __syncthreads();
        bf16x8 af[4], bfv[4];
        #pragma unroll
        for (int f = 0; f < 4; f++) {
            af[f]  = *(const bf16x8*)&As[(wm + f*16 + (lane&15))*32 + (lane>>4)*8];
            bfv[f] = *(const bf16x8*)&Bs[(wn + f*16 + (lane&15))*32 + (lane>>4)*8];
        }
        #pragma unroll
        for (int fi = 0; fi < 4; fi++)
            #pragma unroll
            for (int fj = 0; fj < 4; fj++)
                acc[fi][fj] = __builtin_amdgcn_mfma_f32_16x16x32_bf16(af[fi], bfv[fj], acc[fi][fj], 0,0,0);
        __syncthreads();
    }
    #pragma unroll
    for (int fj = 0; fj < 4; fj++) {
        const int col = n0 + wn + fj*16 + (lane & 15);
        const float s = g[col] * rsqrtf(vr[col] + EPS_);
        const float o = bb[col] - mn[col] * s;
        const bool vcol = (col - (col/80)*80) >= 16;
        #pragma unroll
        for (int fi = 0; fi < 4; fi++)
            #pragma unroll
            for (int r = 0; r < 4; r++) {
                const int m = m0 + wm + fi*16 + (lane>>4)*4 + r;
                float v = acc[fi][fj][r] * s + o;
                if (vcol) v = v * fminf(fmaxf(v + 3.f, 0.f), 6.f) * (1.f/6.f);
                outC[(size_t)m * HKV_ + col] = bfr(v);
            }
    }
}

// ---------------- K2: q = BN(text @ q_w^T) -> f32 (NT_ x 128) ----------------
__global__ __launch_bounds__(128) void k2_q(
    const float* __restrict__ text, const float* __restrict__ q_w,
    const float* __restrict__ g, const float* __restrict__ bb,
    const float* __restrict__ mn, const float* __restrict__ vr,
    float* __restrict__ q_out)
{
    __shared__ float ts[DIM_];
    const int t = blockIdx.x, j = threadIdx.x;
    for (int i = threadIdx.x; i < DIM_; i += 128) ts[i] = text[t * DIM_ + i];
    __syncthreads();
    float acc = 0.f;
    for (int k = 0; k < DIM_; k++) acc += ts[k] * q_w[j * DIM_ + k];
    const float s = g[j] * rsqrtf(vr[j] + EPS_);
    q_out[t * 128 + j] = acc * s + (bb[j] - mn[j] * s);
}

// -------- K3a: rowsums of exp(qk*0.25 + bias) per (b,h); writes 1/sum --------
// MFMA 16x16x32: A = Q [112][32] zero-padded (cols 16..31 = 0), B = K rows.
__global__ __launch_bounds__(256) void k3a(
    const unsigned short* __restrict__ kvf, const float* __restrict__ qb,
    const float* __restrict__ biases, const int* __restrict__ Wp,
    float* __restrict__ wsinv)
{
    __shared__ unsigned short Kl[N_*16];   // [1024 n][16 d] bf16, 32 KB
    __shared__ unsigned short Ql[112*32];  // [112 t][32 k] zero-padded, 7 KB
    __shared__ unsigned short bsl[3200];   // bias bf16
    const int bh = blockIdx.x, b = bh >> 3, h = bh & 7;
    const int tid = threadIdx.x;
    const int wave = tid >> 6, lane = tid & 63;
    const int w = *Wp;

    // stage K via global_load_lds (linear dest)
    #pragma unroll
    for (int i = 0; i < 8; i++) {
        const int C = i*256 + tid;
        const int n = C >> 1, half = C & 1;
        GLDS16(kvf + (size_t)(b*N_ + n)*HKV_ + h*80 + half*8, Kl + (i*256 + wave*64)*8);
    }
    for (int i = tid; i < 112*32; i += 256) {
        const int t = i >> 5, d = i & 31;
        Ql[i] = (t < NT_ && d < 16) ? bfr(qb[t*128 + h*16 + d]) : (unsigned short)0;
    }
    for (int i = tid; i < 3200; i += 256) bsl[i] = bfr(biases[h*10000 + i]);
    __syncthreads();

    const int kg = lane >> 4;
    for (int tt = wave; tt < 7; tt += 4) {
        bf16x8 qf = *(const bf16x8*)&Ql[(tt*16 + (lane&15))*32 + kg*8];
        float rs[4] = {0.f,0.f,0.f,0.f};
        const int tb = tt*16 + ((lane>>4)<<2);
        for (int nt = 0; nt < 64; nt++) {
            const int n = nt*16 + (lane & 15);
            bf16x8 kf = *(const bf16x8*)&Kl[n*16 + (kg&1)*8];
            f32x4 a = __builtin_amdgcn_mfma_f32_16x16x32_bf16(qf, kf, (f32x4){0.f,0.f,0.f,0.f}, 0,0,0);
            const int px = n / w;
            const int py = n - px*w;
            const int pxm = px*100;
            #pragma unroll
            for (int r = 0; r < 4; r++) {
                int dy = iabs(tb + r - py); dy = dy > 99 ? 99 : dy;
                rs[r] += __expf(fmaf(a[r], 0.25f, bfl(bsl[pxm + dy])));
            }
        }
        #pragma unroll
        for (int r = 0; r < 4; r++) {
            #pragma unroll
            for (int msk = 1; msk < 16; msk <<= 1) rs[r] += __shfl_xor(rs[r], msk);
        }
        if ((lane & 15) == 0) {
            #pragma unroll
            for (int r = 0; r < 4; r++)
                wsinv[(size_t)bh*112 + tb + r] = 1.0f / rs[r];
        }
    }
}

// -------- K3b: P = hswish(exp(logit)*inv) -> attn_t [b][n][h*100+t] bf16 -----
// MFMA 16x16x32: A = K rows (n = M dim, XOR-swizzled granules), B = Q.
__global__ __launch_bounds__(256) void k3b(
    const unsigned short* __restrict__ kvf, const float* __restrict__ qb,
    const float* __restrict__ biases, const int* __restrict__ Wp,
    const float* __restrict__ wsinv, unsigned short* __restrict__ attn_t)
{
    __shared__ unsigned short Kl[128*128];   // [128 n][16 granules of 8] swizzled, 32 KB
    __shared__ unsigned short Ql[112*128];   // [112 t][16 granules of 8] swizzled, 28 KB
    __shared__ unsigned short bsl[4000];     // [5 px][8 h][100 dy] bf16, 8 KB
    __shared__ float invs[800];              // [8 h][100 t]
    __shared__ unsigned short zbuf[8];
    const int bx = blockIdx.x, b = bx >> 3, n0 = (bx & 7) * 128;
    const int tid = threadIdx.x;
    const int wave = tid >> 6, lane = tid & 63;
    const int w = *Wp;
    const int pxlo = n0 / w;

    if (tid < 8) zbuf[tid] = 0;
    // stage K: pre-swizzled global source, linear LDS dest
    #pragma unroll
    for (int i = 0; i < 8; i++) {
        const int C = i*256 + tid;
        const int n = C >> 4, gslot = C & 15;
        const int h2g = gslot ^ (n & 7);
        GLDS16(kvf + (size_t)(b*N_ + n0 + n)*HKV_ + (h2g>>1)*80 + (h2g&1)*8,
               Kl + (i*256 + wave*64)*8);
    }
    // stage Q (f32 -> bf16, swizzled granules)
    for (int G = tid; G < 1792; G += 256) {
        const int t = G >> 4, dg = G & 15;
        ushort4 o0 = {0,0,0,0}, o1 = {0,0,0,0};
        if (t < NT_) {
            const float* src = qb + t*128 + dg*8;
            float4 v0 = *(const float4*)src, v1 = *(const float4*)(src+4);
            o0.x=bfr(v0.x); o0.y=bfr(v0.y); o0.z=bfr(v0.z); o0.w=bfr(v0.w);
            o1.x=bfr(v1.x); o1.y=bfr(v1.y); o1.z=bfr(v1.z); o1.w=bfr(v1.w);
        }
        unsigned short* dst = &Ql[t*128 + (dg ^ (t & 7))*8];
        *(ushort4*)dst = o0; *(ushort4*)(dst+4) = o1;
    }
    for (int i = tid; i < 4000; i += 256) {
        const int pr = i / 800, rem = i - pr*800;
        const int h = rem / 100, dy = rem - h*100;
        int row = pxlo + pr; row = row > 99 ? 99 : row;
        bsl[i] = bfr(biases[h*10000 + row*100 + dy]);
    }
    for (int i = tid; i < 800; i += 256) {
        const int h = i / 100, t = i - h*100;
        invs[i] = wsinv[(size_t)(b*8 + h)*112 + t];
    }
    __syncthreads();

    const int kg = lane >> 4;
    const int l7 = lane & 7;
    for (int nn = wave; nn < 8; nn += 4) {
        const int ngb = n0 + nn*16 + ((lane>>4)<<2);
        int prx[4], pyv[4];
        #pragma unroll
        for (int r = 0; r < 4; r++) {
            const int ng = ngb + r;
            const int px = ng / w;
            prx[r] = px - pxlo;
            pyv[r] = ng - px*w;
        }
        const int t = (lane & 15);  // t offset within tile added later
        for (int h = 0; h < 8; h++) {
            const int nloc = nn*16 + (lane & 15);
            const unsigned short* aptr = (kg < 2)
                ? &Kl[nloc*128 + ((((h<<1)|kg) ^ l7))*8] : zbuf;
            bf16x8 kf = *(const bf16x8*)aptr;
            for (int tt = 0; tt < 7; tt++) {
                const int tc = tt*16 + t;
                bf16x8 qf = *(const bf16x8*)&Ql[tc*128 + ((((h<<1)|(kg&1)) ^ l7))*8];
                f32x4 a = __builtin_amdgcn_mfma_f32_16x16x32_bf16(kf, qf, (f32x4){0.f,0.f,0.f,0.f}, 0,0,0);
                const int tcl = tc > 99 ? 99 : tc;
                const float invv = invs[h*100 + tcl];
                if (tc < NT_) {
                    #pragma unroll
                    for (int r = 0; r < 4; r++) {
                        int dy = iabs(tc - pyv[r]); dy = dy > 99 ? 99 : dy;
                        const float bb = bfl(bsl[(prx[r]*8 + h)*100 + dy]);
                        const float e = __expf(fmaf(a[r], 0.25f, bb));
                        const float p = e * invv;
                        const float hs = p * (p + 3.f) * (1.f/6.f);
                        attn_t[(size_t)(b*N_ + ngb + r)*800 + h*100 + tc] = bfr(hs);
                    }
                }
            }
        }
    }
}

// -------- K4: out = BN(A @ proj_w^T), A = [hswish(v) | attn_t], all GLDS -----
__global__ __launch_bounds__(512,2) void k4g(
    const unsigned short* __restrict__ kvf, const unsigned short* __restrict__ attn_t,
    const unsigned short* __restrict__ pwb,
    const float* __restrict__ g, const float* __restrict__ bb,
    const float* __restrict__ mn, const float* __restrict__ vr,
    float* __restrict__ out)
{
    __shared__ unsigned short As[128*32];
    __shared__ unsigned short Bs[256*32];
    const int tid = threadIdx.x;
    const int wave = tid >> 6, lane = tid & 63;
    const int m0 = blockIdx.x * 128;
    const int wm = (wave >> 2) * 64, wn = (wave & 3) * 64;
    const int arow = tid >> 2, ac8 = (tid & 3) * 8;
    f32x4 acc[4][4];
    #pragma unroll
    for (int i=0;i<4;i++)
        #pragma unroll
        for (int j=0;j<4;j++) acc[i][j] = (f32x4){0.f,0.f,0.f,0.f};

    for (int ks = 0; ks < KCAT_/32; ks++) {
        const int k0 = ks * 32;
        // A tile 128x32 via GLDS: 1 chunk per thread
        {
            const size_t mrow = (size_t)(m0 + arow);
            const unsigned short* src;
            if (k0 < DH_) {
                const int h = k0 >> 6;
                src = kvf + mrow*HKV_ + h*80 + 16 + (k0 & 32) + ac8;
            } else {
                src = attn_t + mrow*800 + (k0 - DH_) + ac8;
            }
            GLDS16(src, As + wave*512);
        }
        // B tile 256x32 via GLDS: 2 chunks per thread
        #pragma unroll
        for (int i = 0; i < 2; i++) {
            const int C = i*512 + tid;
            const int row = C >> 2, c8 = (C & 3)*8;
            GLDS16(pwb + (size_t)row*KCAT_ + k0 + c8, Bs + (i*512 + wave*64)*8);
        }
        __syncthreads();
        bf16x8 af[4], bfv[4];
        #pragma unroll
        for (int f = 0; f < 4; f++) {
            af[f]  = *(const bf16x8*)&As[(wm + f*16 + (lane&15))*32 + (lane>>4)*8];
            bfv[f] = *(const bf16x8*)&Bs[(wn + f*16 + (lane&15))*32 + (lane>>4)*8];
        }
        #pragma unroll
        for (int fi = 0; fi < 4; fi++)
            #pragma unroll
            for (int fj = 0; fj < 4; fj++)
                acc[fi][fj] = __builtin_amdgcn_mfma_f32_16x16x32_bf16(af[fi], bfv[fj], acc[fi][fj], 0,0,0);
        __syncthreads();
    }
    #pragma unroll
    for (int fj = 0; fj < 4; fj++) {
        const int col = wn + fj*16 + (lane & 15);
        const float s = g[col] * rsqrtf(vr[col] + EPS_);
        const float o = bb[col] - mn[col] * s;
        #pragma unroll
        for (int fi = 0; fi < 4; fi++)
            #pragma unroll
            for (int r = 0; r < 4; r++) {
                const int m = m0 + wm + fi*16 + (lane>>4)*4 + r;
                out[(size_t)m * DIM_ + col] = acc[fi][fj][r] * s + o;
            }
    }
}

extern "C" void kernel_launch(void* const* d_in, const int* in_sizes, int n_in,
                              void* d_out, int out_size, void* d_ws, size_t ws_size,
                              hipStream_t stream) {
    const float* x      = (const float*)d_in[0];
    const float* text   = (const float*)d_in[1];
    const float* kv_w   = (const float*)d_in[2];
    const float* kv_g   = (const float*)d_in[3];
    const float* kv_b   = (const float*)d_in[4];
    const float* kv_m   = (const float*)d_in[5];
    const float* kv_v   = (const float*)d_in[6];
    const float* q_w    = (const float*)d_in[7];
    const float* q_g    = (const float*)d_in[8];
    const float* q_b    = (const float*)d_in[9];
    const float* q_m    = (const float*)d_in[10];
    const float* q_v    = (const float*)d_in[11];
    const float* proj_w = (const float*)d_in[12];
    const float* proj_g = (const float*)d_in[13];
    const float* proj_b = (const float*)d_in[14];
    const float* proj_m = (const float*)d_in[15];
    const float* proj_v = (const float*)d_in[16];
    const float* biases = (const float*)d_in[17];
    const int*   Wp     = (const int*)d_in[19];
    float* out = (float*)d_out;

    char* w = (char*)d_ws;
    size_t off = 0;
    auto alloc = [&](size_t bytes) { void* p = w + off; off += (bytes + 255) & ~255ull; return p; };
    unsigned short* xb    = (unsigned short*)alloc((size_t)M_*DIM_*2);       // 33.6 MB
    unsigned short* kvwb  = (unsigned short*)alloc((size_t)HKV_*DIM_*2);
    unsigned short* pwb   = (unsigned short*)alloc((size_t)DIM_*KCAT_*2);
    unsigned short* kvbuf = (unsigned short*)alloc((size_t)M_*HKV_*2);       // 83.9 MB
    unsigned short* attnt = (unsigned short*)alloc((size_t)M_*800*2);        // 104.9 MB
    float*          qbuf  = (float*)alloc((size_t)NT_*128*4);
    float*          wsinv = (float*)alloc((size_t)B_*NH_*112*4);

    p0_cvt<<<2048, 256, 0, stream>>>(x, kv_w, proj_w, xb, kvwb, pwb);
    k1g<<<dim3(HKV_/128, M_/128), 256, 0, stream>>>(xb, kvwb, kv_g, kv_b, kv_m, kv_v, kvbuf);
    k2_q<<<NT_, 128, 0, stream>>>(text, q_w, q_g, q_b, q_m, q_v, qbuf);
    k3a<<<B_*NH_, 256, 0, stream>>>(kvbuf, qbuf, biases, Wp, wsinv);
    k3b<<<B_*NH_, 256, 0, stream>>>(kvbuf, qbuf, biases, Wp, wsinv, attnt);
    k4g<<<M_/128, 512, 0, stream>>>(kvbuf, attnt, pwb, proj_g, proj_b, proj_m, proj_v, out);
}

// Round 6
// 371.818 us; speedup vs baseline: 3.2295x; 1.0083x over previous
//
#include <hip/hip_runtime.h>
#include <hip/hip_bf16.h>

#define B_    64
#define N_    1024
#define NT_   100
#define DIM_  256
#define KD_   16
#define NH_   8
#define D_    64
#define DH_   512
#define HKV_  640
#define PROJIN_ 1512
#define KCAT_ 1312
#define EPS_  1e-5f
#define M_    (B_*N_)

typedef __attribute__((ext_vector_type(8))) short bf16x8;
typedef __attribute__((ext_vector_type(4))) float f32x4;

__device__ __forceinline__ int iabs(int x){ return x<0?-x:x; }
__device__ __forceinline__ unsigned short bfr(float f){ __hip_bfloat16 h=__float2bfloat16(f); return *(unsigned short*)&h; }
__device__ __forceinline__ float bfl(unsigned short u){ union{unsigned int i;float f;}c; c.i=(unsigned int)u<<16; return c.f; }

#define GLDS16(src, dst) __builtin_amdgcn_global_load_lds( \
    (const __attribute__((address_space(1))) void*)(src),  \
    (__attribute__((address_space(3))) void*)(dst), 16, 0, 0)

// ---------------- P0: weights f32 -> bf16 (kv_w, proj_w only) ----------------
__global__ __launch_bounds__(256) void p0_cvt(
    const float* __restrict__ kvw, const float* __restrict__ pw,
    unsigned short* __restrict__ kvwb, unsigned short* __restrict__ pwb)
{
    const size_t stride = (size_t)gridDim.x * 256;
    const size_t i0 = (size_t)blockIdx.x * 256 + threadIdx.x;
    for (size_t q = i0; q < (size_t)HKV_*DIM_/4; q += stride) {
        float4 v = ((const float4*)kvw)[q];
        ushort4 o; o.x=bfr(v.x); o.y=bfr(v.y); o.z=bfr(v.z); o.w=bfr(v.w);
        ((ushort4*)kvwb)[q] = o;
    }
    for (size_t q = i0; q < (size_t)DIM_*KCAT_/4; q += stride) {
        const int row = (int)(q / (KCAT_/4)), cq = (int)(q % (KCAT_/4));
        float4 v = ((const float4*)(pw + (size_t)row*PROJIN_))[cq];
        ushort4 o; o.x=bfr(v.x); o.y=bfr(v.y); o.z=bfr(v.z); o.w=bfr(v.w);
        ((ushort4*)pwb)[q] = o;
    }
}

// -------- K1: kv = BN(x @ kv_w^T); hswish on v; split kbuf/vbuf outputs ------
__global__ __launch_bounds__(256,2) void k1g(
    const float* __restrict__ x, const unsigned short* __restrict__ wb,
    const float* __restrict__ g, const float* __restrict__ bb,
    const float* __restrict__ mn, const float* __restrict__ vr,
    unsigned short* __restrict__ kb, unsigned short* __restrict__ vb)
{
    __shared__ unsigned short As[128*32];
    __shared__ unsigned short Bs[128*32];
    __shared__ unsigned short Ls[64*128];
    const int tid = threadIdx.x;
    const int wave = tid >> 6, lane = tid & 63;
    // XCD-chunked swizzle: 2560 blocks = 8 XCDs x 320; n varies fastest inside a chunk
    const int logical = (blockIdx.x & 7) * 320 + (blockIdx.x >> 3);
    const int nblk = logical % 5, mblk = logical / 5;
    const int m0 = mblk * 128, n0 = nblk * 128;
    const int wm = (wave >> 1) * 64, wn = (wave & 1) * 64;
    const int srow = lane >> 2, scol = (lane & 3) * 8;
    const int sr = tid >> 1, sh = (tid & 1) * 16;     // A reg-stage: row, col-half
    f32x4 acc[4][4];
    #pragma unroll
    for (int i=0;i<4;i++)
        #pragma unroll
        for (int j=0;j<4;j++) acc[i][j] = (f32x4){0.f,0.f,0.f,0.f};

    for (int k0 = 0; k0 < DIM_; k0 += 32) {
        // B tile via async GLDS
        #pragma unroll
        for (int i = 0; i < 2; i++) {
            const int rr = (wave*2 + i)*16 + srow;
            GLDS16(wb + (size_t)(n0+rr)*DIM_ + k0 + scol, Bs + (wave*2+i)*512);
        }
        // A tile: f32 load + convert + ds_write (16 cols per thread)
        {
            const float* xs = x + (size_t)(m0+sr)*DIM_ + k0 + sh;
            float4 v0 = ((const float4*)xs)[0], v1 = ((const float4*)xs)[1];
            float4 v2 = ((const float4*)xs)[2], v3 = ((const float4*)xs)[3];
            ushort4 a0, a1, b0, b1;
            a0.x=bfr(v0.x); a0.y=bfr(v0.y); a0.z=bfr(v0.z); a0.w=bfr(v0.w);
            a1.x=bfr(v1.x); a1.y=bfr(v1.y); a1.z=bfr(v1.z); a1.w=bfr(v1.w);
            b0.x=bfr(v2.x); b0.y=bfr(v2.y); b0.z=bfr(v2.z); b0.w=bfr(v2.w);
            b1.x=bfr(v3.x); b1.y=bfr(v3.y); b1.z=bfr(v3.z); b1.w=bfr(v3.w);
            *(ushort4*)&As[sr*32 + sh]      = a0;
            *(ushort4*)&As[sr*32 + sh + 4]  = a1;
            *(ushort4*)&As[sr*32 + sh + 8]  = b0;
            *(ushort4*)&As[sr*32 + sh + 12] = b1;
        }
        __syncthreads();
        bf16x8 af[4], bfv[4];
        #pragma unroll
        for (int f = 0; f < 4; f++) {
            af[f]  = *(const bf16x8*)&As[(wm + f*16 + (lane&15))*32 + (lane>>4)*8];
            bfv[f] = *(const bf16x8*)&Bs[(wn + f*16 + (lane&15))*32 + (lane>>4)*8];
        }
        #pragma unroll
        for (int fi = 0; fi < 4; fi++)
            #pragma unroll
            for (int fj = 0; fj < 4; fj++)
                acc[fi][fj] = __builtin_amdgcn_mfma_f32_16x16x32_bf16(af[fi], bfv[fj], acc[fi][fj], 0,0,0);
        __syncthreads();
    }

    // Epilogue: BN + hswish(v) -> Ls (64x128) -> packed b128 stores, 2 passes
    #pragma unroll
    for (int pass = 0; pass < 2; ++pass) {
        if ((wave >> 1) == pass) {
            #pragma unroll
            for (int fj = 0; fj < 4; fj++) {
                const int col = wn + fj*16 + (lane & 15);
                const int gcol = n0 + col;
                const float s = g[gcol] * rsqrtf(vr[gcol] + EPS_);
                const float o = bb[gcol] - mn[gcol] * s;
                const bool vcol = (gcol - (gcol/80)*80) >= 16;
                #pragma unroll
                for (int fi = 0; fi < 4; fi++)
                    #pragma unroll
                    for (int r = 0; r < 4; r++) {
                        float v = acc[fi][fj][r] * s + o;
                        if (vcol) v = v * fminf(fmaxf(v + 3.f, 0.f), 6.f) * (1.f/6.f);
                        Ls[(fi*16 + (lane>>4)*4 + r)*128 + col] = bfr(v);
                    }
            }
        }
        __syncthreads();
        #pragma unroll
        for (int it = 0; it < 4; ++it) {
            const int row = it*16 + (tid >> 4);
            const int c8  = tid & 15;
            bf16x8 val = *(const bf16x8*)&Ls[row*128 + c8*8];
            const int gcol = n0 + c8*8;
            const int h = gcol / 80, rem = gcol - h*80;
            const int m = m0 + pass*64 + row;
            unsigned short* dst = (rem < 16)
                ? (kb + (size_t)m*128 + h*16 + rem)
                : (vb + (size_t)m*512 + h*64 + (rem - 16));
            *(bf16x8*)dst = val;
        }
        __syncthreads();
    }
}

// ---------------- K2: q = BN(text @ q_w^T) -> f32 (NT_ x 128) ----------------
__global__ __launch_bounds__(128) void k2_q(
    const float* __restrict__ text, const float* __restrict__ q_w,
    const float* __restrict__ g, const float* __restrict__ bb,
    const float* __restrict__ mn, const float* __restrict__ vr,
    float* __restrict__ q_out)
{
    __shared__ float ts[DIM_];
    const int t = blockIdx.x, j = threadIdx.x;
    for (int i = threadIdx.x; i < DIM_; i += 128) ts[i] = text[t * DIM_ + i];
    __syncthreads();
    float acc = 0.f;
    for (int k = 0; k < DIM_; k++) acc += ts[k] * q_w[j * DIM_ + k];
    const float s = g[j] * rsqrtf(vr[j] + EPS_);
    q_out[t * 128 + j] = acc * s + (bb[j] - mn[j] * s);
}

// -------- K3a: rowsums of exp(qk*0.25 + bias) per (b,h); writes 1/sum --------
__global__ __launch_bounds__(256) void k3a(
    const unsigned short* __restrict__ kb, const float* __restrict__ qb,
    const float* __restrict__ biases, const int* __restrict__ Wp,
    float* __restrict__ wsinv)
{
    __shared__ unsigned short Kl[N_*16];
    __shared__ unsigned short Ql[112*32];
    __shared__ unsigned short bsl[3200];
    const int bh = blockIdx.x, b = bh >> 3, h = bh & 7;
    const int tid = threadIdx.x;
    const int wave = tid >> 6, lane = tid & 63;
    const int w = *Wp;

    #pragma unroll
    for (int i = 0; i < 8; i++) {
        const int C = i*256 + tid;
        const int n = C >> 1, half = C & 1;
        GLDS16(kb + (size_t)(b*N_ + n)*128 + h*16 + half*8, Kl + (i*256 + wave*64)*8);
    }
    for (int i = tid; i < 112*32; i += 256) {
        const int t = i >> 5, d = i & 31;
        Ql[i] = (t < NT_ && d < 16) ? bfr(qb[t*128 + h*16 + d]) : (unsigned short)0;
    }
    for (int i = tid; i < 3200; i += 256) bsl[i] = bfr(biases[h*10000 + i]);
    __syncthreads();

    const int kg = lane >> 4;
    for (int tt = wave; tt < 7; tt += 4) {
        bf16x8 qf = *(const bf16x8*)&Ql[(tt*16 + (lane&15))*32 + kg*8];
        float rs[4] = {0.f,0.f,0.f,0.f};
        const int tb = tt*16 + ((lane>>4)<<2);
        for (int nt = 0; nt < 64; nt++) {
            const int n = nt*16 + (lane & 15);
            bf16x8 kf = *(const bf16x8*)&Kl[n*16 + (kg&1)*8];
            f32x4 a = __builtin_amdgcn_mfma_f32_16x16x32_bf16(qf, kf, (f32x4){0.f,0.f,0.f,0.f}, 0,0,0);
            const int px = n / w;
            const int py = n - px*w;
            const int pxm = px*100;
            #pragma unroll
            for (int r = 0; r < 4; r++) {
                int dy = iabs(tb + r - py); dy = dy > 99 ? 99 : dy;
                rs[r] += __expf(fmaf(a[r], 0.25f, bfl(bsl[pxm + dy])));
            }
        }
        #pragma unroll
        for (int r = 0; r < 4; r++) {
            #pragma unroll
            for (int msk = 1; msk < 16; msk <<= 1) rs[r] += __shfl_xor(rs[r], msk);
        }
        if ((lane & 15) == 0) {
            #pragma unroll
            for (int r = 0; r < 4; r++)
                wsinv[(size_t)bh*112 + tb + r] = 1.0f / rs[r];
        }
    }
}

// -------- K3b: P = hswish(exp(logit)*inv) -> attn_t [b][n][h*100+t] bf16 -----
// A = Q (rows t, zero-padded K=32), B = K (cols n). Lane owns 4 consecutive t.
__global__ __launch_bounds__(256) void k3b(
    const unsigned short* __restrict__ kb, const float* __restrict__ qb,
    const float* __restrict__ biases, const int* __restrict__ Wp,
    const float* __restrict__ wsinv, unsigned short* __restrict__ attn_t)
{
    __shared__ unsigned short Kl[128*128];   // [128 n][16 granule slots of 8] swizzled
    __shared__ unsigned short Ql[112*128];   // [112 t][16 granule slots of 8] swizzled
    __shared__ unsigned short bsl[4000];     // [5 px][8 h][100 dy]
    __shared__ float invs[800];              // [8 h][100 t]
    __shared__ unsigned short zbuf[8];
    const int bx = blockIdx.x, b = bx >> 3, n0 = (bx & 7) * 128;
    const int tid = threadIdx.x;
    const int wave = tid >> 6, lane = tid & 63;
    const int w = *Wp;
    const int pxlo = n0 / w;

    if (tid < 8) zbuf[tid] = 0;
    #pragma unroll
    for (int i = 0; i < 8; i++) {
        const int C = i*256 + tid;
        const int n = C >> 4, gslot = C & 15;
        const int h2g = gslot ^ (n & 7);
        GLDS16(kb + (size_t)(b*N_ + n0 + n)*128 + h2g*8, Kl + (i*256 + wave*64)*8);
    }
    for (int G = tid; G < 1792; G += 256) {
        const int t = G >> 4, dg = G & 15;
        ushort4 o0 = {0,0,0,0}, o1 = {0,0,0,0};
        if (t < NT_) {
            const float* src = qb + t*128 + dg*8;
            float4 v0 = *(const float4*)src, v1 = *(const float4*)(src+4);
            o0.x=bfr(v0.x); o0.y=bfr(v0.y); o0.z=bfr(v0.z); o0.w=bfr(v0.w);
            o1.x=bfr(v1.x); o1.y=bfr(v1.y); o1.z=bfr(v1.z); o1.w=bfr(v1.w);
        }
        unsigned short* dst = &Ql[t*128 + (dg ^ (t & 7))*8];
        *(ushort4*)dst = o0; *(ushort4*)(dst+4) = o1;
    }
    for (int i = tid; i < 4000; i += 256) {
        const int pr = i / 800, rem = i - pr*800;
        const int h = rem / 100, dy = rem - h*100;
        int row = pxlo + pr; row = row > 99 ? 99 : row;
        bsl[i] = bfr(biases[h*10000 + row*100 + dy]);
    }
    for (int i = tid; i < 800; i += 256) {
        const int h = i / 100, t = i - h*100;
        invs[i] = wsinv[(size_t)(b*8 + h)*112 + t];
    }
    __syncthreads();

    const int kg = lane >> 4;
    const int l15 = lane & 15, l7 = lane & 7;
    #pragma unroll
    for (int nn2 = 0; nn2 < 2; nn2++) {
        const int nn = wave + nn2*4;
        const int ng = n0 + nn*16 + l15;
        const int px = ng / w;
        const int prx = px - pxlo, py = ng - px*w;
        const size_t obase = (size_t)(b*N_ + ng)*800;
        const int nloc = nn*16 + l15;
        for (int h = 0; h < 8; h++) {
            const int h2 = h*2;
            bf16x8 kf = *(const bf16x8*)&Kl[nloc*128 + ((h2 | (kg&1)) ^ l7)*8];
            for (int tt = 0; tt < 7; tt++) {
                const int trow = tt*16 + l15;
                const unsigned short* aptr = (kg < 2)
                    ? &Ql[trow*128 + (((h2 | kg) ^ l7))*8] : zbuf;
                bf16x8 qf = *(const bf16x8*)aptr;
                f32x4 a = __builtin_amdgcn_mfma_f32_16x16x32_bf16(qf, kf, (f32x4){0.f,0.f,0.f,0.f}, 0,0,0);
                const int tb0 = tt*16 + (kg << 2);
                if (tb0 < NT_) {
                    ushort4 pk;
                    unsigned short* pkp = (unsigned short*)&pk;
                    #pragma unroll
                    for (int r = 0; r < 4; r++) {
                        const int t = tb0 + r;
                        int dy = iabs(t - py); dy = dy > 99 ? 99 : dy;
                        const float bbv = bfl(bsl[(prx*8 + h)*100 + dy]);
                        const float e = __expf(fmaf(a[r], 0.25f, bbv));
                        const float p = e * invs[h*100 + t];
                        pkp[r] = bfr(p * (p + 3.f) * (1.f/6.f));
                    }
                    *(ushort4*)(attn_t + obase + h*100 + tb0) = pk;
                }
            }
        }
    }
}

// -------- K4: out = BN(A @ proj_w^T), A = [vbuf | attn_t], all GLDS ----------
__global__ __launch_bounds__(512,2) void k4g(
    const unsigned short* __restrict__ vb, const unsigned short* __restrict__ attn_t,
    const unsigned short* __restrict__ pwb,
    const float* __restrict__ g, const float* __restrict__ bb,
    const float* __restrict__ mn, const float* __restrict__ vr,
    float* __restrict__ out)
{
    __shared__ unsigned short As[128*32];
    __shared__ unsigned short Bs[256*32];
    const int tid = threadIdx.x;
    const int wave = tid >> 6, lane = tid & 63;
    const int m0 = blockIdx.x * 128;
    const int wm = (wave >> 2) * 64, wn = (wave & 3) * 64;
    const int arow = tid >> 2, ac8 = (tid & 3) * 8;
    f32x4 acc[4][4];
    #pragma unroll
    for (int i=0;i<4;i++)
        #pragma unroll
        for (int j=0;j<4;j++) acc[i][j] = (f32x4){0.f,0.f,0.f,0.f};

    for (int ks = 0; ks < KCAT_/32; ks++) {
        const int k0 = ks * 32;
        {
            const size_t mrow = (size_t)(m0 + arow);
            const unsigned short* src = (k0 < DH_)
                ? (vb + mrow*512 + k0 + ac8)
                : (attn_t + mrow*800 + (k0 - DH_) + ac8);
            GLDS16(src, As + wave*512);
        }
        #pragma unroll
        for (int i = 0; i < 2; i++) {
            const int C = i*512 + tid;
            const int row = C >> 2, c8 = (C & 3)*8;
            GLDS16(pwb + (size_t)row*KCAT_ + k0 + c8, Bs + (i*512 + wave*64)*8);
        }
        __syncthreads();
        bf16x8 af[4], bfv[4];
        #pragma unroll
        for (int f = 0; f < 4; f++) {
            af[f]  = *(const bf16x8*)&As[(wm + f*16 + (lane&15))*32 + (lane>>4)*8];
            bfv[f] = *(const bf16x8*)&Bs[(wn + f*16 + (lane&15))*32 + (lane>>4)*8];
        }
        #pragma unroll
        for (int fi = 0; fi < 4; fi++)
            #pragma unroll
            for (int fj = 0; fj < 4; fj++)
                acc[fi][fj] = __builtin_amdgcn_mfma_f32_16x16x32_bf16(af[fi], bfv[fj], acc[fi][fj], 0,0,0);
        __syncthreads();
    }
    #pragma unroll
    for (int fj = 0; fj < 4; fj++) {
        const int col = wn + fj*16 + (lane & 15);
        const float s = g[col] * rsqrtf(vr[col] + EPS_);
        const float o = bb[col] - mn[col] * s;
        #pragma unroll
        for (int fi = 0; fi < 4; fi++)
            #pragma unroll
            for (int r = 0; r < 4; r++) {
                const int m = m0 + wm + fi*16 + (lane>>4)*4 + r;
                out[(size_t)m * DIM_ + col] = acc[fi][fj][r] * s + o;
            }
    }
}

extern "C" void kernel_launch(void* const* d_in, const int* in_sizes, int n_in,
                              void* d_out, int out_size, void* d_ws, size_t ws_size,
                              hipStream_t stream) {
    const float* x      = (const float*)d_in[0];
    const float* text   = (const float*)d_in[1];
    const float* kv_w   = (const float*)d_in[2];
    const float* kv_g   = (const float*)d_in[3];
    const float* kv_b   = (const float*)d_in[4];
    const float* kv_m   = (const float*)d_in[5];
    const float* kv_v   = (const float*)d_in[6];
    const float* q_w    = (const float*)d_in[7];
    const float* q_g    = (const float*)d_in[8];
    const float* q_b    = (const float*)d_in[9];
    const float* q_m    = (const float*)d_in[10];
    const float* q_v    = (const float*)d_in[11];
    const float* proj_w = (const float*)d_in[12];
    const float* proj_g = (const float*)d_in[13];
    const float* proj_b = (const float*)d_in[14];
    const float* proj_m = (const float*)d_in[15];
    const float* proj_v = (const float*)d_in[16];
    const float* biases = (const float*)d_in[17];
    const int*   Wp     = (const int*)d_in[19];
    float* out = (float*)d_out;

    char* w = (char*)d_ws;
    size_t off = 0;
    auto alloc = [&](size_t bytes) { void* p = w + off; off += (bytes + 255) & ~255ull; return p; };
    unsigned short* kvwb  = (unsigned short*)alloc((size_t)HKV_*DIM_*2);
    unsigned short* pwb   = (unsigned short*)alloc((size_t)DIM_*KCAT_*2);
    unsigned short* kbuf  = (unsigned short*)alloc((size_t)M_*128*2);     // 16.8 MB
    unsigned short* vbuf  = (unsigned short*)alloc((size_t)M_*512*2);     // 67.1 MB
    unsigned short* attnt = (unsigned short*)alloc((size_t)M_*800*2);     // 104.9 MB
    float*          qbuf  = (float*)alloc((size_t)NT_*128*4);
    float*          wsinv = (float*)alloc((size_t)B_*NH_*112*4);

    p0_cvt<<<256, 256, 0, stream>>>(kv_w, proj_w, kvwb, pwb);
    k1g<<<2560, 256, 0, stream>>>(x, kvwb, kv_g, kv_b, kv_m, kv_v, kbuf, vbuf);
    k2_q<<<NT_, 128, 0, stream>>>(text, q_w, q_g, q_b, q_m, q_v, qbuf);
    k3a<<<B_*NH_, 256, 0, stream>>>(kbuf, qbuf, biases, Wp, wsinv);
    k3b<<<B_*NH_, 256, 0, stream>>>(kbuf, qbuf, biases, Wp, wsinv, attnt);
    k4g<<<M_/128, 512, 0, stream>>>(vbuf, attnt, pwb, proj_g, proj_b, proj_m, proj_v, out);
}

// Round 8
// 349.802 us; speedup vs baseline: 3.4327x; 1.0629x over previous
//
#include <hip/hip_runtime.h>
#include <hip/hip_bf16.h>

#define B_    64
#define N_    1024
#define NT_   100
#define DIM_  256
#define KD_   16
#define NH_   8
#define D_    64
#define DH_   512
#define HKV_  640
#define PROJIN_ 1512
#define KCAT_ 1312
#define EPS_  1e-5f
#define M_    (B_*N_)

typedef __attribute__((ext_vector_type(8))) short bf16x8;
typedef __attribute__((ext_vector_type(4))) float f32x4;

__device__ __forceinline__ int iabs(int x){ return x<0?-x:x; }
__device__ __forceinline__ unsigned short bfr(float f){ __hip_bfloat16 h=__float2bfloat16(f); return *(unsigned short*)&h; }
__device__ __forceinline__ float bfl(unsigned short u){ union{unsigned int i;float f;}c; c.i=(unsigned int)u<<16; return c.f; }
// ushort offset of the 16B chunk (row, slot) with slot-XOR swizzle: 8-way -> 2-way frag reads
__device__ __forceinline__ int swzofs(int row, int slot){ return (row*4 + (slot ^ ((row>>1)&3)))*8; }

#define GLDS16(src, dst) __builtin_amdgcn_global_load_lds( \
    (const __attribute__((address_space(1))) void*)(src),  \
    (__attribute__((address_space(3))) void*)(dst), 16, 0, 0)

// ---------------- P0: weights f32 -> bf16 (kv_w, proj_w only) ----------------
__global__ __launch_bounds__(256) void p0_cvt(
    const float* __restrict__ kvw, const float* __restrict__ pw,
    unsigned short* __restrict__ kvwb, unsigned short* __restrict__ pwb)
{
    const size_t stride = (size_t)gridDim.x * 256;
    const size_t i0 = (size_t)blockIdx.x * 256 + threadIdx.x;
    for (size_t q = i0; q < (size_t)HKV_*DIM_/4; q += stride) {
        float4 v = ((const float4*)kvw)[q];
        ushort4 o; o.x=bfr(v.x); o.y=bfr(v.y); o.z=bfr(v.z); o.w=bfr(v.w);
        ((ushort4*)kvwb)[q] = o;
    }
    for (size_t q = i0; q < (size_t)DIM_*KCAT_/4; q += stride) {
        const int row = (int)(q / (KCAT_/4)), cq = (int)(q % (KCAT_/4));
        float4 v = ((const float4*)(pw + (size_t)row*PROJIN_))[cq];
        ushort4 o; o.x=bfr(v.x); o.y=bfr(v.y); o.z=bfr(v.z); o.w=bfr(v.w);
        ((ushort4*)pwb)[q] = o;
    }
}

// -------- K1: kv = BN(x @ kv_w^T); hswish on v; split kbuf/vbuf --------------
// Pipelined: x reg-prefetch + counted vmcnt(2) (B-GLDS oldest, order pinned).
__global__ __launch_bounds__(256,4) void k1g(
    const float* __restrict__ x, const unsigned short* __restrict__ wb,
    const float* __restrict__ g, const float* __restrict__ bb,
    const float* __restrict__ mn, const float* __restrict__ vr,
    unsigned short* __restrict__ kb, unsigned short* __restrict__ vb)
{
    __shared__ unsigned short sbuf[8192];   // As[0:4096) Bs[4096:8192); Ls overlay (epilogue)
    unsigned short* As = sbuf;
    unsigned short* Bs = sbuf + 4096;
    const int tid = threadIdx.x;
    const int wave = tid >> 6, lane = tid & 63;
    const int logical = (blockIdx.x & 7) * 320 + (blockIdx.x >> 3);  // 2560 = 8 XCD x 320
    const int nblk = logical % 5, mblk = logical / 5;
    const int m0 = mblk * 128, n0 = nblk * 128;
    const int wm = (wave >> 1) * 64, wn = (wave & 1) * 64;
    const int arow = tid >> 2, aslot = tid & 3;   // A chunk c: row = arow + c*64
    f32x4 acc[4][4];
    #pragma unroll
    for (int i=0;i<4;i++)
        #pragma unroll
        for (int j=0;j<4;j++) acc[i][j] = (f32x4){0.f,0.f,0.f,0.f};

    float4 xv[2][2][2];
    #pragma unroll
    for (int c = 0; c < 2; c++) {
        const float4* p = (const float4*)(x + (size_t)(m0 + arow + c*64)*DIM_ + aslot*8);
        xv[0][c][0] = p[0]; xv[0][c][1] = p[1];
    }

    #pragma unroll
    for (int ks = 0; ks < 8; ks++) {
        const int k0 = ks*32;
        if (ks) __builtin_amdgcn_s_barrier();
        // B tile via GLDS FIRST (must be the oldest vmem ops)
        #pragma unroll
        for (int i = 0; i < 2; i++) {
            const int C = i*256 + tid;
            const int row = C>>2, slot = C&3;
            GLDS16(wb + (size_t)(n0+row)*DIM_ + k0 + ((slot ^ ((row>>1)&3))<<3),
                   Bs + (i*256 + wave*64)*8);
        }
        __builtin_amdgcn_sched_barrier(0);   // pin: B-GLDS issued before x loads
        // prefetch next x into regs (left in flight across the barrier)
        if (ks < 7) {
            #pragma unroll
            for (int c = 0; c < 2; c++) {
                const float4* p = (const float4*)(x + (size_t)(m0 + arow + c*64)*DIM_ + k0 + 32 + aslot*8);
                xv[(ks+1)&1][c][0] = p[0]; xv[(ks+1)&1][c][1] = p[1];
            }
        }
        __builtin_amdgcn_sched_barrier(0);   // pin: x loads issued before the waitcnt
        // A: cvt prefetched regs -> swizzled ds_write (conflict-free linear chunks)
        #pragma unroll
        for (int c = 0; c < 2; c++) {
            const int row = arow + c*64;
            float4 v0 = xv[ks&1][c][0], v1 = xv[ks&1][c][1];
            ushort4 lo, hi;
            lo.x=bfr(v0.x); lo.y=bfr(v0.y); lo.z=bfr(v0.z); lo.w=bfr(v0.w);
            hi.x=bfr(v1.x); hi.y=bfr(v1.y); hi.z=bfr(v1.z); hi.w=bfr(v1.w);
            unsigned short* d = &As[swzofs(row, aslot)];
            *(ushort4*)d = lo; *(ushort4*)(d+4) = hi;
        }
        // drain the 2 B-GLDS (oldest) + all ds_writes; leave the 2 x-prefetches in flight
        if (ks < 7) asm volatile("s_waitcnt vmcnt(2) lgkmcnt(0)" ::: "memory");
        else        asm volatile("s_waitcnt vmcnt(0) lgkmcnt(0)" ::: "memory");
        __builtin_amdgcn_sched_barrier(0);
        __builtin_amdgcn_s_barrier();

        bf16x8 af[4], bfv[4];
        #pragma unroll
        for (int f = 0; f < 4; f++) {
            af[f]  = *(const bf16x8*)&As[swzofs(wm + f*16 + (lane&15), lane>>4)];
            bfv[f] = *(const bf16x8*)&Bs[swzofs(wn + f*16 + (lane&15), lane>>4)];
        }
        #pragma unroll
        for (int fi = 0; fi < 4; fi++)
            #pragma unroll
            for (int fj = 0; fj < 4; fj++)
                acc[fi][fj] = __builtin_amdgcn_mfma_f32_16x16x32_bf16(af[fi], bfv[fj], acc[fi][fj], 0,0,0);
    }
    __syncthreads();   // all MFMA frag reads done before Ls overlay

    unsigned short* Ls = sbuf;   // 64 x 128
    #pragma unroll
    for (int pass = 0; pass < 2; ++pass) {
        if ((wave >> 1) == pass) {
            #pragma unroll
            for (int fj = 0; fj < 4; fj++) {
                const int col = wn + fj*16 + (lane & 15);
                const int gcol = n0 + col;
                const float s = g[gcol] * rsqrtf(vr[gcol] + EPS_);
                const float o = bb[gcol] - mn[gcol] * s;
                const bool vcol = (gcol - (gcol/80)*80) >= 16;
                #pragma unroll
                for (int fi = 0; fi < 4; fi++)
                    #pragma unroll
                    for (int r = 0; r < 4; r++) {
                        float v = acc[fi][fj][r] * s + o;
                        if (vcol) v = v * fminf(fmaxf(v + 3.f, 0.f), 6.f) * (1.f/6.f);
                        Ls[(fi*16 + (lane>>4)*4 + r)*128 + col] = bfr(v);
                    }
            }
        }
        __syncthreads();
        #pragma unroll
        for (int it = 0; it < 4; ++it) {
            const int row = it*16 + (tid >> 4);
            const int c8  = tid & 15;
            bf16x8 val = *(const bf16x8*)&Ls[row*128 + c8*8];
            const int gcol = n0 + c8*8;
            const int h = gcol / 80, rem = gcol - h*80;
            const int m = m0 + pass*64 + row;
            unsigned short* dst = (rem < 16)
                ? (kb + (size_t)m*128 + h*16 + rem)
                : (vb + (size_t)m*512 + h*64 + (rem - 16));
            *(bf16x8*)dst = val;
        }
        __syncthreads();
    }
}

// ---------------- K2: q = BN(text @ q_w^T) -> f32 (NT_ x 128) ----------------
__global__ __launch_bounds__(128) void k2_q(
    const float* __restrict__ text, const float* __restrict__ q_w,
    const float* __restrict__ g, const float* __restrict__ bb,
    const float* __restrict__ mn, const float* __restrict__ vr,
    float* __restrict__ q_out)
{
    __shared__ float ts[DIM_];
    const int t = blockIdx.x, j = threadIdx.x;
    for (int i = threadIdx.x; i < DIM_; i += 128) ts[i] = text[t * DIM_ + i];
    __syncthreads();
    float acc = 0.f;
    for (int k = 0; k < DIM_; k++) acc += ts[k] * q_w[j * DIM_ + k];
    const float s = g[j] * rsqrtf(vr[j] + EPS_);
    q_out[t * 128 + j] = acc * s + (bb[j] - mn[j] * s);
}

// -------- K3f: one pass: e = exp(qk*0.25+bias) -> attn_t; rowsum -> 1/sum ----
// A = Q (rows t, zero-padded K=32), B = K. Lane owns 4 consecutive t at one n.
__global__ __launch_bounds__(256) void k3f(
    const unsigned short* __restrict__ kb, const float* __restrict__ qb,
    const float* __restrict__ biases, const int* __restrict__ Wp,
    float* __restrict__ wsinv, unsigned short* __restrict__ attn_t)
{
    __shared__ unsigned short Kl[N_*16];   // 32 KB
    __shared__ unsigned short Ql[112*32];  // 7 KB (zero-padded)
    __shared__ unsigned short bsl[3200];   // 6.4 KB
    const int bh = blockIdx.x, b = bh >> 3, h = bh & 7;
    const int tid = threadIdx.x;
    const int wave = tid >> 6, lane = tid & 63;
    const int w = *Wp;

    #pragma unroll
    for (int i = 0; i < 8; i++) {
        const int C = i*256 + tid;
        const int n = C >> 1, half = C & 1;
        GLDS16(kb + (size_t)(b*N_ + n)*128 + h*16 + half*8, Kl + (i*256 + wave*64)*8);
    }
    for (int i = tid; i < 112*32; i += 256) {
        const int t = i >> 5, d = i & 31;
        Ql[i] = (t < NT_ && d < 16) ? bfr(qb[t*128 + h*16 + d]) : (unsigned short)0;
    }
    for (int i = tid; i < 3200; i += 256) bsl[i] = bfr(biases[h*10000 + i]);
    __syncthreads();

    const int kg = lane >> 4;
    for (int tt = wave; tt < 7; tt += 4) {
        bf16x8 qf = *(const bf16x8*)&Ql[(tt*16 + (lane&15))*32 + kg*8];
        float rs[4] = {0.f,0.f,0.f,0.f};
        const int tb = tt*16 + (kg<<2);
        const bool doStore = tb < NT_;
        for (int nt = 0; nt < 64; nt++) {
            const int n = nt*16 + (lane & 15);
            bf16x8 kf = *(const bf16x8*)&Kl[n*16 + (kg&1)*8];
            f32x4 a = __builtin_amdgcn_mfma_f32_16x16x32_bf16(qf, kf, (f32x4){0.f,0.f,0.f,0.f}, 0,0,0);
            const int px = n / w;
            const int py = n - px*w;
            const int pxm = px*100;
            ushort4 pk;
            unsigned short* pkp = (unsigned short*)&pk;
            #pragma unroll
            for (int r = 0; r < 4; r++) {
                int dy = iabs(tb + r - py); dy = dy > 99 ? 99 : dy;
                const float e = __expf(fmaf(a[r], 0.25f, bfl(bsl[pxm + dy])));
                rs[r] += e;
                pkp[r] = bfr(e);
            }
            if (doStore)
                *(ushort4*)(attn_t + (size_t)(b*N_ + n)*800 + h*100 + tb) = pk;
        }
        #pragma unroll
        for (int r = 0; r < 4; r++) {
            #pragma unroll
            for (int msk = 1; msk < 16; msk <<= 1) rs[r] += __shfl_xor(rs[r], msk);
        }
        if ((lane & 15) == 0) {
            #pragma unroll
            for (int r = 0; r < 4; r++)
                wsinv[(size_t)bh*112 + tb + r] = 1.0f / rs[r];
        }
    }
}

// -------- K4: out = BN(A @ proj_w^T); A = [v | hswish(e*inv)]; dbuf pipeline -
__global__ __launch_bounds__(512,2) void k4g(
    const unsigned short* __restrict__ vb, const unsigned short* __restrict__ et,
    const unsigned short* __restrict__ pwb, const float* __restrict__ wsinvf,
    const float* __restrict__ g, const float* __restrict__ bb,
    const float* __restrict__ mn, const float* __restrict__ vr,
    float* __restrict__ out)
{
    __shared__ unsigned short AS[2][4096];   // 2 x 8 KB  (128 x 32)
    __shared__ unsigned short BS[2][8192];   // 2 x 16 KB (256 x 32)
    __shared__ float invf[800];
    const int tid = threadIdx.x;
    const int wave = tid >> 6, lane = tid & 63;
    const int m0 = blockIdx.x * 128;
    const int b  = blockIdx.x >> 3;
    const int wm = (wave >> 2) * 64, wn = (wave & 3) * 64;
    const int arow = tid >> 2, aslot = tid & 3;
    f32x4 acc[4][4];
    #pragma unroll
    for (int i=0;i<4;i++)
        #pragma unroll
        for (int j=0;j<4;j++) acc[i][j] = (f32x4){0.f,0.f,0.f,0.f};

    for (int i = tid; i < 800; i += 512) {
        const int h = i / 100;
        invf[i] = wsinvf[(size_t)(b*8 + h)*112 + (i - h*100)];
    }
    // prologue: stage tile 0 (v-region)
    {
        GLDS16(vb + (size_t)(m0+arow)*512 + ((aslot ^ ((arow>>1)&3))<<3), AS[0] + wave*512);
        #pragma unroll
        for (int i = 0; i < 2; i++) {
            const int C = i*512 + tid;
            const int row = C>>2, slot = C&3;
            GLDS16(pwb + (size_t)row*KCAT_ + ((slot ^ ((row>>1)&3))<<3), BS[0] + (i*512 + wave*64)*8);
        }
    }
    asm volatile("s_waitcnt vmcnt(0)" ::: "memory");
    __builtin_amdgcn_s_barrier();

    for (int ks = 0; ks < 41; ks++) {
        const int cur = ks & 1, nxt = cur ^ 1;
        const bool hasNext = (ks < 40);
        uint4 ev;
        bool nextAttn = false;
        if (hasNext) {
            const int k0n = (ks+1)*32;
            if (k0n >= DH_) {   // e-load into regs, finish after MFMA
                nextAttn = true;
                ev = *(const uint4*)(et + (size_t)(m0+arow)*800 + (k0n - DH_) + aslot*8);
            } else {
                GLDS16(vb + (size_t)(m0+arow)*512 + k0n + ((aslot ^ ((arow>>1)&3))<<3),
                       AS[nxt] + wave*512);
            }
            #pragma unroll
            for (int i = 0; i < 2; i++) {
                const int C = i*512 + tid;
                const int row = C>>2, slot = C&3;
                GLDS16(pwb + (size_t)row*KCAT_ + k0n + ((slot ^ ((row>>1)&3))<<3),
                       BS[nxt] + (i*512 + wave*64)*8);
            }
        }
        // compute current tile
        bf16x8 af[4], bfv[4];
        #pragma unroll
        for (int f = 0; f < 4; f++) {
            af[f]  = *(const bf16x8*)&AS[cur][swzofs(wm + f*16 + (lane&15), lane>>4)];
            bfv[f] = *(const bf16x8*)&BS[cur][swzofs(wn + f*16 + (lane&15), lane>>4)];
        }
        #pragma unroll
        for (int fi = 0; fi < 4; fi++)
            #pragma unroll
            for (int fj = 0; fj < 4; fj++)
                acc[fi][fj] = __builtin_amdgcn_mfma_f32_16x16x32_bf16(af[fi], bfv[fj], acc[fi][fj], 0,0,0);
        // finish attn staging: normalize + hswish + swizzled ds_write
        if (nextAttn) {
            const int cb = (ks+1)*32 - DH_ + aslot*8;
            float4 iv0 = *(const float4*)&invf[cb];
            float4 iv1 = *(const float4*)&invf[cb+4];
            const float iv[8] = {iv0.x,iv0.y,iv0.z,iv0.w,iv1.x,iv1.y,iv1.z,iv1.w};
            const unsigned short* u16 = (const unsigned short*)&ev;
            unsigned short o[8];
            #pragma unroll
            for (int j = 0; j < 8; j++) {
                const float p = bfl(u16[j]) * iv[j];
                o[j] = bfr(p * (p + 3.f) * (1.f/6.f));
            }
            unsigned short* d = &AS[nxt][swzofs(arow, aslot)];
            *(ushort4*)d = *(ushort4*)&o[0];
            *(ushort4*)(d+4) = *(ushort4*)&o[4];
        }
        asm volatile("s_waitcnt vmcnt(0) lgkmcnt(0)" ::: "memory");
        __builtin_amdgcn_s_barrier();
    }

    #pragma unroll
    for (int fj = 0; fj < 4; fj++) {
        const int col = wn + fj*16 + (lane & 15);
        const float s = g[col] * rsqrtf(vr[col] + EPS_);
        const float o = bb[col] - mn[col] * s;
        #pragma unroll
        for (int fi = 0; fi < 4; fi++)
            #pragma unroll
            for (int r = 0; r < 4; r++) {
                const int m = m0 + wm + fi*16 + (lane>>4)*4 + r;
                out[(size_t)m * DIM_ + col] = acc[fi][fj][r] * s + o;
            }
    }
}

extern "C" void kernel_launch(void* const* d_in, const int* in_sizes, int n_in,
                              void* d_out, int out_size, void* d_ws, size_t ws_size,
                              hipStream_t stream) {
    const float* x      = (const float*)d_in[0];
    const float* text   = (const float*)d_in[1];
    const float* kv_w   = (const float*)d_in[2];
    const float* kv_g   = (const float*)d_in[3];
    const float* kv_b   = (const float*)d_in[4];
    const float* kv_m   = (const float*)d_in[5];
    const float* kv_v   = (const float*)d_in[6];
    const float* q_w    = (const float*)d_in[7];
    const float* q_g    = (const float*)d_in[8];
    const float* q_b    = (const float*)d_in[9];
    const float* q_m    = (const float*)d_in[10];
    const float* q_v    = (const float*)d_in[11];
    const float* proj_w = (const float*)d_in[12];
    const float* proj_g = (const float*)d_in[13];
    const float* proj_b = (const float*)d_in[14];
    const float* proj_m = (const float*)d_in[15];
    const float* proj_v = (const float*)d_in[16];
    const float* biases = (const float*)d_in[17];
    const int*   Wp     = (const int*)d_in[19];
    float* out = (float*)d_out;

    char* w = (char*)d_ws;
    size_t off = 0;
    auto alloc = [&](size_t bytes) { void* p = w + off; off += (bytes + 255) & ~255ull; return p; };
    unsigned short* kvwb  = (unsigned short*)alloc((size_t)HKV_*DIM_*2);
    unsigned short* pwb   = (unsigned short*)alloc((size_t)DIM_*KCAT_*2);
    unsigned short* kbuf  = (unsigned short*)alloc((size_t)M_*128*2);     // 16.8 MB
    unsigned short* vbuf  = (unsigned short*)alloc((size_t)M_*512*2);     // 67.1 MB
    unsigned short* attnt = (unsigned short*)alloc((size_t)M_*800*2);     // 104.9 MB (e values)
    float*          qbuf  = (float*)alloc((size_t)NT_*128*4);
    float*          wsinv = (float*)alloc((size_t)B_*NH_*112*4);

    p0_cvt<<<256, 256, 0, stream>>>(kv_w, proj_w, kvwb, pwb);
    k1g<<<2560, 256, 0, stream>>>(x, kvwb, kv_g, kv_b, kv_m, kv_v, kbuf, vbuf);
    k2_q<<<NT_, 128, 0, stream>>>(text, q_w, q_g, q_b, q_m, q_v, qbuf);
    k3f<<<B_*NH_, 256, 0, stream>>>(kbuf, qbuf, biases, Wp, wsinv, attnt);
    k4g<<<M_/128, 512, 0, stream>>>(vbuf, attnt, pwb, wsinv, proj_g, proj_b, proj_m, proj_v, out);
}